// Round 13
// baseline (177.770 us; speedup 1.0000x reference)
//
#include <hip/hip_runtime.h>
#include <hip/hip_fp16.h>

// DeductronCTC v12 (512-thread paired-chunk persistent K1, 24 waves/CU):
//   K0: pre-pack WL|WR and W_logit into MFMA fragment layout (f16) in ws.
//   K1: persistent 768 blocks x 512 thr; waves 0-3 -> chunk 2p, waves 4-7 ->
//       chunk 2p+1 sharing one 32KB LDS W tile. Emits per-row chunk-exclusive
//       prefix transforms (PA,PB) f16-packed (16B/lane) + chunk summaries.
//   K3: 2-level scan of chunk summaries -> u0 (chunk-start states).
//   K4: z = PA*u0 + PB, logits MFMA, nontemporal pre loads + out stores.
// Replay-safe: no buffer both read+written by a kernel, no aliasing.

constexpr int NF  = 500000;
constexpr int KIN = 128;
constexpr int M   = 64;
constexpr int CH  = 64;
constexpr int NC  = (NF + CH - 1) / CH;   // 7813
constexpr int NPAIR = (NC + 1) / 2;       // 3907
constexpr int NG  = (NC + 63) / 64;       // 123
constexpr int GPW = (NG + 3) / 4;         // 31
constexpr int K1BLOCKS = 768;             // 3 blocks/CU * 256 CU

typedef _Float16 f16x8 __attribute__((ext_vector_type(8)));
typedef __fp16   fp16x2 __attribute__((ext_vector_type(2)));
typedef float    f32x4 __attribute__((ext_vector_type(4)));

__device__ __forceinline__ float sig(float x) {
    return __builtin_amdgcn_rcpf(1.0f + __expf(-x));
}

// ---------------------------------------------------------------- K0
__global__ void k0_pack(const float* __restrict__ WL, const float* __restrict__ WR,
                        const float* __restrict__ WLog,
                        _Float16* __restrict__ wpre, _Float16* __restrict__ wlogpre)
{
    int flat = blockIdx.x * 1024 + threadIdx.x * 4;
    if (flat < 16384) {
        int k = flat >> 7, col = flat & 127;
        float4 v = (col < 64) ? *(const float4*)&WL[k * 64 + col]
                              : *(const float4*)&WR[k * 64 + (col - 64)];
        int kb = k >> 3, kj = k & 7;
        wpre[(kb * 128 + col + 0) * 8 + kj] = (_Float16)v.x;
        wpre[(kb * 128 + col + 1) * 8 + kj] = (_Float16)v.y;
        wpre[(kb * 128 + col + 2) * 8 + kj] = (_Float16)v.z;
        wpre[(kb * 128 + col + 3) * 8 + kj] = (_Float16)v.w;
    } else if (flat < 16384 + 4096) {
        int f2 = flat - 16384;
        int k = f2 >> 6, c = f2 & 63;
        float4 v = *(const float4*)&WLog[f2];
        int kb = k >> 3, kj = k & 7;
        wlogpre[(kb * 64 + c + 0) * 8 + kj] = (_Float16)v.x;
        wlogpre[(kb * 64 + c + 1) * 8 + kj] = (_Float16)v.y;
        wlogpre[(kb * 64 + c + 2) * 8 + kj] = (_Float16)v.z;
        wlogpre[(kb * 64 + c + 3) * 8 + kj] = (_Float16)v.w;
    }
}

// ---------------------------------------------------------------- K1
__global__ __launch_bounds__(512, 6)
void k1_prefix(const float* __restrict__ X, const _Float16* __restrict__ wpre,
               const float* __restrict__ bL, const float* __restrict__ bR,
               float* __restrict__ sA, float* __restrict__ sB,
               _Float16* __restrict__ pre)
{
    __shared__ _Float16 w_s[16384];          // 32 KB B-frags, staged ONCE
    __shared__ float pA_s[512], pB_s[512];   // per-half wave totals
    const int tid  = threadIdx.x;
    const int lane = tid & 63;
    const int wall = tid >> 6;               // 0..7
    const int w    = wall & 3;               // wave within chunk
    const int half = wall >> 2;              // which chunk of the pair
    const int arow = lane & 15, kb = lane >> 4;

    #pragma unroll
    for (int i = 0; i < 4; ++i) {
        int c16 = i * 512 + tid;
        *(f16x8*)&w_s[c16 * 8] = ((const f16x8*)wpre)[c16];
    }
    __syncthreads();

    float blv[4], brv[4];
    #pragma unroll
    for (int c = 0; c < 4; ++c) { blv[c] = bL[c * 16 + arow]; brv[c] = bR[c * 16 + arow]; }

    for (int pair = blockIdx.x; pair < NPAIR; pair += K1BLOCKS) {
        const int cid = 2 * pair + half;
        const bool valid = cid < NC;
        const int t0 = cid * CH;

        // ---- load X rows direct (8 x f32x4), then MFMA
        const int xrow = t0 + w * 16 + arow;
        const float* xp = X + (size_t)xrow * KIN;
        const bool rowok = valid && (xrow < NF);
        f32x4 xv[8];
        #pragma unroll
        for (int s = 0; s < 4; ++s) {
            xv[2 * s]     = rowok ? *(const f32x4*)&xp[s * 32 + kb * 8]
                                  : (f32x4){0.f, 0.f, 0.f, 0.f};
            xv[2 * s + 1] = rowok ? *(const f32x4*)&xp[s * 32 + kb * 8 + 4]
                                  : (f32x4){0.f, 0.f, 0.f, 0.f};
        }
        f32x4 acc[8];
        #pragma unroll
        for (int c = 0; c < 8; ++c) acc[c] = (f32x4){0.f, 0.f, 0.f, 0.f};
        #pragma unroll
        for (int s = 0; s < 4; ++s) {
            fp16x2 p0 = __builtin_amdgcn_cvt_pkrtz(xv[2 * s].x, xv[2 * s].y);
            fp16x2 p1 = __builtin_amdgcn_cvt_pkrtz(xv[2 * s].z, xv[2 * s].w);
            fp16x2 p2 = __builtin_amdgcn_cvt_pkrtz(xv[2 * s + 1].x, xv[2 * s + 1].y);
            fp16x2 p3 = __builtin_amdgcn_cvt_pkrtz(xv[2 * s + 1].z, xv[2 * s + 1].w);
            f16x8 af = { (_Float16)p0[0], (_Float16)p0[1],
                         (_Float16)p1[0], (_Float16)p1[1],
                         (_Float16)p2[0], (_Float16)p2[1],
                         (_Float16)p3[0], (_Float16)p3[1] };
            #pragma unroll
            for (int c = 0; c < 8; ++c) {
                f16x8 bf = *(const f16x8*)&w_s[((s * 4 + kb) * 128 + c * 16 + arow) * 8];
                acc[c] = __builtin_amdgcn_mfma_f32_16x16x32_f16(af, bf, acc[c], 0, 0, 0);
            }
        }

        // ---- sigmoid epilogue: a,b in registers
        float a[4][4], b[4][4];
        #pragma unroll
        for (int c = 0; c < 4; ++c) {
            #pragma unroll
            for (int reg = 0; reg < 4; ++reg) {
                float lv = sig(acc[c][reg] + blv[c]);
                float rv = sig(acc[c + 4][reg] + brv[c]);
                a[c][reg] = lv * rv;
                b[c][reg] = 1.0f - lv;
            }
        }

        // ---- local 4-row compose + 2-step kb-group shfl scan (inclusive)
        float Ai[4], Bi[4];
        #pragma unroll
        for (int c = 0; c < 4; ++c) {
            float A = 1.f, B = 0.f;
            #pragma unroll
            for (int reg = 0; reg < 4; ++reg) {
                if (t0 + w * 16 + kb * 4 + reg < NF - 1) {
                    B = fmaf(a[c][reg], B, b[c][reg]);
                    A *= a[c][reg];
                }
            }
            Ai[c] = A; Bi[c] = B;
        }
        #pragma unroll
        for (int d = 16; d < 64; d <<= 1) {
            #pragma unroll
            for (int c = 0; c < 4; ++c) {
                float pA = __shfl_up(Ai[c], d), pB = __shfl_up(Bi[c], d);
                if (lane >= d) { Bi[c] = fmaf(Ai[c], pB, Bi[c]); Ai[c] *= pA; }
            }
        }

        // exclusive within-wave prefix
        float eA[4], eB[4];
        #pragma unroll
        for (int c = 0; c < 4; ++c) {
            eA[c] = __shfl_up(Ai[c], 16);
            eB[c] = __shfl_up(Bi[c], 16);
            if (kb == 0) { eA[c] = 1.f; eB[c] = 0.f; }
        }
        if (kb == 3) {   // wave totals (per half)
            #pragma unroll
            for (int c = 0; c < 4; ++c) {
                pA_s[half * 256 + w * 64 + c * 16 + arow] = Ai[c];
                pB_s[half * 256 + w * 64 + c * 16 + arow] = Bi[c];
            }
        }
        __syncthreads();

        // compose prior-wave totals within own half
        float EA[4] = {1.f, 1.f, 1.f, 1.f}, EB[4] = {0.f, 0.f, 0.f, 0.f};
        for (int s2 = 0; s2 < w; ++s2) {
            #pragma unroll
            for (int c = 0; c < 4; ++c) {
                float qa = pA_s[half * 256 + s2 * 64 + c * 16 + arow];
                float qb = pB_s[half * 256 + s2 * 64 + c * 16 + arow];
                EB[c] = fmaf(qa, EB[c], qb);
                EA[c] *= qa;
            }
        }
        // per-row chunk-exclusive prefix; 4 rows' (PA,PB) -> one 16B store
        if (valid) {
            _Float16* prebase = pre + (size_t)cid * 8192;
            #pragma unroll
            for (int c = 0; c < 4; ++c) {
                float pa = eA[c] * EA[c];
                float pb = fmaf(eA[c], EB[c], eB[c]);
                f16x8 sv;
                #pragma unroll
                for (int reg = 0; reg < 4; ++reg) {
                    fp16x2 pp = __builtin_amdgcn_cvt_pkrtz(pa, pb);
                    sv[2 * reg]     = (_Float16)pp[0];
                    sv[2 * reg + 1] = (_Float16)pp[1];
                    if (t0 + w * 16 + kb * 4 + reg < NF - 1) {
                        pb = fmaf(a[c][reg], pb, b[c][reg]);
                        pa *= a[c][reg];
                    }
                }
                *(f16x8*)&prebase[((((w * 4 + kb) * 4 + c) * 16 + arow) * 4) * 2] = sv;
            }
        }
        // chunk summary -> sA,sB (first wave of each half)
        if (w == 0 && valid) {
            float At = 1.f, Bt = 0.f;
            #pragma unroll
            for (int s2 = 0; s2 < 4; ++s2) {
                float qa = pA_s[half * 256 + s2 * 64 + lane];
                float qb = pB_s[half * 256 + s2 * 64 + lane];
                Bt = fmaf(qa, Bt, qb);
                At *= qa;
            }
            sA[lane * NC + cid] = At;
            sB[lane * NC + cid] = Bt;
        }
        __syncthreads();   // protect pA_s/pB_s for next iteration
    }
}

// ---------------------------------------------------------------- K3
__global__ __launch_bounds__(256)
void k3_scan(const float* __restrict__ sA, const float* __restrict__ sB,
             float* __restrict__ u0)
{
    __shared__ float tA_s[4], tB_s[4];
    const int j    = blockIdx.x;
    const int lane = threadIdx.x & 63;
    const int w    = threadIdx.x >> 6;

    float PA[GPW], PB[GPW];
    float cA = 1.f, cB = 0.f;
    #pragma unroll
    for (int g = 0; g < GPW; ++g) {
        int c = (w * GPW + g) * 64 + lane;
        float A = 1.f, B = 0.f;
        if (c < NC) { A = sA[j * NC + c]; B = sB[j * NC + c]; }
        #pragma unroll
        for (int d = 1; d < 64; d <<= 1) {
            float pA = __shfl_up(A, d), pB = __shfl_up(B, d);
            if (lane >= d) { B = fmaf(A, pB, B); A *= pA; }
        }
        float eA = __shfl_up(A, 1), eB = __shfl_up(B, 1);
        if (lane == 0) { eA = 1.f; eB = 0.f; }
        PA[g] = eA * cA;
        PB[g] = fmaf(eA, cB, eB);
        float tA = __shfl(A, 63), tB = __shfl(B, 63);
        cB = fmaf(tA, cB, tB);
        cA *= tA;
    }
    if (lane == 0) { tA_s[w] = cA; tB_s[w] = cB; }
    __syncthreads();
    float uw = 0.f;
    for (int s2 = 0; s2 < w; ++s2) uw = fmaf(tA_s[s2], uw, tB_s[s2]);
    #pragma unroll
    for (int g = 0; g < GPW; ++g) {
        int c = (w * GPW + g) * 64 + lane;
        if (c < NC) u0[c * M + j] = fmaf(PA[g], uw, PB[g]);
    }
}

// ---------------------------------------------------------------- K4
__global__ __launch_bounds__(256, 8)
void k4_light(const _Float16* __restrict__ pre, const float* __restrict__ u0,
              const _Float16* __restrict__ wlogpre, const float* __restrict__ bLog,
              float* __restrict__ out)
{
    __shared__ _Float16 z_s[64 * 72];
    const int tid = threadIdx.x, lane = tid & 63, w = tid >> 6;
    const int arow = lane & 15, kb = lane >> 4;
    const int t0 = blockIdx.x * CH;

    float u0v[4];
    #pragma unroll
    for (int c = 0; c < 4; ++c) u0v[c] = u0[blockIdx.x * 64 + c * 16 + arow];

    const _Float16* prebase = pre + (size_t)blockIdx.x * 8192;
    #pragma unroll
    for (int c = 0; c < 4; ++c) {
        f16x8 pv = __builtin_nontemporal_load(
            (const f16x8*)&prebase[((((w * 4 + kb) * 4 + c) * 16 + arow) * 4) * 2]);
        #pragma unroll
        for (int reg = 0; reg < 4; ++reg) {
            int rl = w * 16 + kb * 4 + reg;
            float z = fmaf((float)pv[2 * reg], u0v[c], (float)pv[2 * reg + 1]);
            z_s[rl * 72 + c * 16 + arow] = (_Float16)z;
        }
    }
    __syncthreads();

    f32x4 acc2[4];
    #pragma unroll
    for (int ct = 0; ct < 4; ++ct) acc2[ct] = (f32x4){0.f, 0.f, 0.f, 0.f};
    #pragma unroll
    for (int ks = 0; ks < 2; ++ks) {
        f16x8 af = *(const f16x8*)&z_s[(w * 16 + arow) * 72 + ks * 32 + kb * 8];
        #pragma unroll
        for (int ct = 0; ct < 4; ++ct) {
            f16x8 bf = *(const f16x8*)&wlogpre[((ks * 4 + kb) * 64 + ct * 16 + arow) * 8];
            acc2[ct] = __builtin_amdgcn_mfma_f32_16x16x32_f16(af, bf, acc2[ct], 0, 0, 0);
        }
    }
    #pragma unroll
    for (int ct = 0; ct < 4; ++ct) {
        float bv = bLog[ct * 16 + arow];
        #pragma unroll
        for (int reg = 0; reg < 4; ++reg) {
            int t = t0 + w * 16 + kb * 4 + reg;
            if (t < NF)
                __builtin_nontemporal_store(acc2[ct][reg] + bv,
                                            &out[t * M + ct * 16 + arow]);
        }
    }
}

// ---------------------------------------------------------------- host
extern "C" void kernel_launch(void* const* d_in, const int* in_sizes, int n_in,
                              void* d_out, int out_size, void* d_ws, size_t ws_size,
                              hipStream_t stream)
{
    const float* X    = (const float*)d_in[0];
    const float* WL   = (const float*)d_in[2];
    const float* bL   = (const float*)d_in[3];
    const float* WR   = (const float*)d_in[4];
    const float* bR   = (const float*)d_in[5];
    const float* WLog = (const float*)d_in[6];
    const float* bLog = (const float*)d_in[7];

    // ws layout (~134 MB):
    _Float16* pre = (_Float16*)d_ws;                       // NC*8192 halfs (128 MB)
    float* sA = (float*)((char*)d_ws + (size_t)NC * 8192 * 2);
    float* sB = sA + (size_t)64 * NC;
    float* u0 = sB + (size_t)64 * NC;
    _Float16* wpre    = (_Float16*)(u0 + (size_t)64 * NC); // 16384 halfs
    _Float16* wlogpre = wpre + 16384;                      // 4096 halfs

    k0_pack<<<20, 256, 0, stream>>>(WL, WR, WLog, wpre, wlogpre);
    k1_prefix<<<K1BLOCKS, 512, 0, stream>>>(X, wpre, bL, bR, sA, sB, pre);
    k3_scan<<<M, 256, 0, stream>>>(sA, sB, u0);
    k4_light<<<NC, 256, 0, stream>>>(pre, u0, wlogpre, bLog, (float*)d_out);
}

// Round 14
// 145.160 us; speedup vs baseline: 1.2247x; 1.2247x over previous
//
#include <hip/hip_runtime.h>
#include <hip/hip_fp16.h>

// DeductronCTC v13 (= v11 + cached pre loads in K4 + 512-thread K3):
//   K0: pre-pack WL|WR and W_logit into MFMA fragment layout (f16) in ws.
//   K1: persistent 1024 blocks; W staged to LDS once per block; grid-stride
//       over chunks with next-chunk X prefetched into registers during the
//       scan/emit epilogue. Emits per-row chunk-exclusive prefix transforms
//       (PA,PB) f16-packed (16B/lane) + chunk summaries.
//   K3: 2-level scan of chunk summaries -> u0 (512 thr, 16 serial groups).
//   K4: z = PA*u0 + PB, logits MFMA; pre loads CACHED (L3-resident from K1),
//       out stores nontemporal (never re-read; preserves L3 for X/pre).
// Replay-safe: no buffer both read+written by a kernel, no aliasing.

constexpr int NF  = 500000;
constexpr int KIN = 128;
constexpr int M   = 64;
constexpr int CH  = 64;
constexpr int NC  = (NF + CH - 1) / CH;   // 7813
constexpr int NG  = (NC + 63) / 64;       // 123
constexpr int K3W = 8;                    // waves per K3 block
constexpr int GPW = (NG + K3W - 1) / K3W; // 16
constexpr int K1GRID = 1024;              // 4 blocks/CU * 256 CU

typedef _Float16 f16x8 __attribute__((ext_vector_type(8)));
typedef __fp16   fp16x2 __attribute__((ext_vector_type(2)));
typedef float    f32x4 __attribute__((ext_vector_type(4)));

__device__ __forceinline__ float sig(float x) {
    return __builtin_amdgcn_rcpf(1.0f + __expf(-x));
}

// ---------------------------------------------------------------- K0
__global__ void k0_pack(const float* __restrict__ WL, const float* __restrict__ WR,
                        const float* __restrict__ WLog,
                        _Float16* __restrict__ wpre, _Float16* __restrict__ wlogpre)
{
    int flat = blockIdx.x * 1024 + threadIdx.x * 4;
    if (flat < 16384) {
        int k = flat >> 7, col = flat & 127;
        float4 v = (col < 64) ? *(const float4*)&WL[k * 64 + col]
                              : *(const float4*)&WR[k * 64 + (col - 64)];
        int kb = k >> 3, kj = k & 7;
        wpre[(kb * 128 + col + 0) * 8 + kj] = (_Float16)v.x;
        wpre[(kb * 128 + col + 1) * 8 + kj] = (_Float16)v.y;
        wpre[(kb * 128 + col + 2) * 8 + kj] = (_Float16)v.z;
        wpre[(kb * 128 + col + 3) * 8 + kj] = (_Float16)v.w;
    } else if (flat < 16384 + 4096) {
        int f2 = flat - 16384;
        int k = f2 >> 6, c = f2 & 63;
        float4 v = *(const float4*)&WLog[f2];
        int kb = k >> 3, kj = k & 7;
        wlogpre[(kb * 64 + c + 0) * 8 + kj] = (_Float16)v.x;
        wlogpre[(kb * 64 + c + 1) * 8 + kj] = (_Float16)v.y;
        wlogpre[(kb * 64 + c + 2) * 8 + kj] = (_Float16)v.z;
        wlogpre[(kb * 64 + c + 3) * 8 + kj] = (_Float16)v.w;
    }
}

// ---------------------------------------------------------------- K1
__global__ __launch_bounds__(256, 4)
void k1_prefix(const float* __restrict__ X, const _Float16* __restrict__ wpre,
               const float* __restrict__ bL, const float* __restrict__ bR,
               float* __restrict__ sA, float* __restrict__ sB,
               _Float16* __restrict__ pre)
{
    __shared__ _Float16 w_s[16384];          // 32 KB B-frags, staged ONCE
    __shared__ float pA_s[256], pB_s[256];
    const int tid = threadIdx.x, lane = tid & 63, w = tid >> 6;
    const int arow = lane & 15, kb = lane >> 4;

    #pragma unroll
    for (int i = 0; i < 8; ++i) {
        int c16 = i * 256 + tid;
        *(f16x8*)&w_s[c16 * 8] = ((const f16x8*)wpre)[c16];
    }
    __syncthreads();

    float blv[4], brv[4];
    #pragma unroll
    for (int c = 0; c < 4; ++c) { blv[c] = bL[c * 16 + arow]; brv[c] = bR[c * 16 + arow]; }

    // prologue: load first chunk's X rows (8 x f32x4 per thread)
    f32x4 xv[8];
    int cid = blockIdx.x;
    {
        const int xrow = cid * CH + w * 16 + arow;
        const float* xp = X + (size_t)xrow * KIN;
        const bool rowok = xrow < NF;
        #pragma unroll
        for (int s = 0; s < 4; ++s) {
            xv[2 * s]     = rowok ? *(const f32x4*)&xp[s * 32 + kb * 8]
                                  : (f32x4){0.f, 0.f, 0.f, 0.f};
            xv[2 * s + 1] = rowok ? *(const f32x4*)&xp[s * 32 + kb * 8 + 4]
                                  : (f32x4){0.f, 0.f, 0.f, 0.f};
        }
    }

    while (cid < NC) {
        const int t0 = cid * CH;
        const int nxt = cid + K1GRID;

        // ---- MFMA on current xv
        f32x4 acc[8];
        #pragma unroll
        for (int c = 0; c < 8; ++c) acc[c] = (f32x4){0.f, 0.f, 0.f, 0.f};
        #pragma unroll
        for (int s = 0; s < 4; ++s) {
            fp16x2 p0 = __builtin_amdgcn_cvt_pkrtz(xv[2 * s].x, xv[2 * s].y);
            fp16x2 p1 = __builtin_amdgcn_cvt_pkrtz(xv[2 * s].z, xv[2 * s].w);
            fp16x2 p2 = __builtin_amdgcn_cvt_pkrtz(xv[2 * s + 1].x, xv[2 * s + 1].y);
            fp16x2 p3 = __builtin_amdgcn_cvt_pkrtz(xv[2 * s + 1].z, xv[2 * s + 1].w);
            f16x8 af = { (_Float16)p0[0], (_Float16)p0[1],
                         (_Float16)p1[0], (_Float16)p1[1],
                         (_Float16)p2[0], (_Float16)p2[1],
                         (_Float16)p3[0], (_Float16)p3[1] };
            #pragma unroll
            for (int c = 0; c < 8; ++c) {
                f16x8 bf = *(const f16x8*)&w_s[((s * 4 + kb) * 128 + c * 16 + arow) * 8];
                acc[c] = __builtin_amdgcn_mfma_f32_16x16x32_f16(af, bf, acc[c], 0, 0, 0);
            }
        }

        // ---- prefetch next chunk's X (latency hidden by epilogue below)
        if (nxt < NC) {
            const int xrow = nxt * CH + w * 16 + arow;
            const float* xp = X + (size_t)xrow * KIN;
            const bool rowok = xrow < NF;
            #pragma unroll
            for (int s = 0; s < 4; ++s) {
                xv[2 * s]     = rowok ? *(const f32x4*)&xp[s * 32 + kb * 8]
                                      : (f32x4){0.f, 0.f, 0.f, 0.f};
                xv[2 * s + 1] = rowok ? *(const f32x4*)&xp[s * 32 + kb * 8 + 4]
                                      : (f32x4){0.f, 0.f, 0.f, 0.f};
            }
        }

        // ---- sigmoid epilogue: a,b in registers
        float a[4][4], b[4][4];
        #pragma unroll
        for (int c = 0; c < 4; ++c) {
            #pragma unroll
            for (int reg = 0; reg < 4; ++reg) {
                float lv = sig(acc[c][reg] + blv[c]);
                float rv = sig(acc[c + 4][reg] + brv[c]);
                a[c][reg] = lv * rv;
                b[c][reg] = 1.0f - lv;
            }
        }

        // ---- local 4-row compose + 2-step kb-group shfl scan (inclusive)
        float Ai[4], Bi[4];
        #pragma unroll
        for (int c = 0; c < 4; ++c) {
            float A = 1.f, B = 0.f;
            #pragma unroll
            for (int reg = 0; reg < 4; ++reg) {
                if (t0 + w * 16 + kb * 4 + reg < NF - 1) {
                    B = fmaf(a[c][reg], B, b[c][reg]);
                    A *= a[c][reg];
                }
            }
            Ai[c] = A; Bi[c] = B;
        }
        #pragma unroll
        for (int d = 16; d < 64; d <<= 1) {
            #pragma unroll
            for (int c = 0; c < 4; ++c) {
                float pA = __shfl_up(Ai[c], d), pB = __shfl_up(Bi[c], d);
                if (lane >= d) { Bi[c] = fmaf(Ai[c], pB, Bi[c]); Ai[c] *= pA; }
            }
        }

        // exclusive within-wave prefix
        float eA[4], eB[4];
        #pragma unroll
        for (int c = 0; c < 4; ++c) {
            eA[c] = __shfl_up(Ai[c], 16);
            eB[c] = __shfl_up(Bi[c], 16);
            if (kb == 0) { eA[c] = 1.f; eB[c] = 0.f; }
        }
        if (kb == 3) {   // wave totals
            #pragma unroll
            for (int c = 0; c < 4; ++c) {
                pA_s[w * 64 + c * 16 + arow] = Ai[c];
                pB_s[w * 64 + c * 16 + arow] = Bi[c];
            }
        }
        __syncthreads();

        // compose prior-wave totals
        float EA[4] = {1.f, 1.f, 1.f, 1.f}, EB[4] = {0.f, 0.f, 0.f, 0.f};
        for (int s2 = 0; s2 < w; ++s2) {
            #pragma unroll
            for (int c = 0; c < 4; ++c) {
                float qa = pA_s[s2 * 64 + c * 16 + arow];
                float qb = pB_s[s2 * 64 + c * 16 + arow];
                EB[c] = fmaf(qa, EB[c], qb);
                EA[c] *= qa;
            }
        }
        // per-row chunk-exclusive prefix; 4 rows' (PA,PB) -> one 16B store
        _Float16* prebase = pre + (size_t)cid * 8192;
        #pragma unroll
        for (int c = 0; c < 4; ++c) {
            float pa = eA[c] * EA[c];
            float pb = fmaf(eA[c], EB[c], eB[c]);
            f16x8 sv;
            #pragma unroll
            for (int reg = 0; reg < 4; ++reg) {
                fp16x2 pp = __builtin_amdgcn_cvt_pkrtz(pa, pb);
                sv[2 * reg]     = (_Float16)pp[0];
                sv[2 * reg + 1] = (_Float16)pp[1];
                if (t0 + w * 16 + kb * 4 + reg < NF - 1) {
                    pb = fmaf(a[c][reg], pb, b[c][reg]);
                    pa *= a[c][reg];
                }
            }
            *(f16x8*)&prebase[((((w * 4 + kb) * 4 + c) * 16 + arow) * 4) * 2] = sv;
        }
        // chunk summary -> sA,sB
        if (tid < 64) {
            float At = 1.f, Bt = 0.f;
            #pragma unroll
            for (int s2 = 0; s2 < 4; ++s2) {
                float qa = pA_s[s2 * 64 + tid], qb = pB_s[s2 * 64 + tid];
                Bt = fmaf(qa, Bt, qb);
                At *= qa;
            }
            sA[tid * NC + cid] = At;
            sB[tid * NC + cid] = Bt;
        }
        __syncthreads();   // protect pA_s/pB_s for next iteration
        cid = nxt;
    }
}

// ---------------------------------------------------------------- K3
__global__ __launch_bounds__(512)
void k3_scan(const float* __restrict__ sA, const float* __restrict__ sB,
             float* __restrict__ u0)
{
    __shared__ float tA_s[K3W], tB_s[K3W];
    const int j    = blockIdx.x;
    const int lane = threadIdx.x & 63;
    const int w    = threadIdx.x >> 6;

    float PA[GPW], PB[GPW];
    float cA = 1.f, cB = 0.f;
    #pragma unroll
    for (int g = 0; g < GPW; ++g) {
        int c = (w * GPW + g) * 64 + lane;
        float A = 1.f, B = 0.f;
        if (c < NC) { A = sA[j * NC + c]; B = sB[j * NC + c]; }
        #pragma unroll
        for (int d = 1; d < 64; d <<= 1) {
            float pA = __shfl_up(A, d), pB = __shfl_up(B, d);
            if (lane >= d) { B = fmaf(A, pB, B); A *= pA; }
        }
        float eA = __shfl_up(A, 1), eB = __shfl_up(B, 1);
        if (lane == 0) { eA = 1.f; eB = 0.f; }
        PA[g] = eA * cA;
        PB[g] = fmaf(eA, cB, eB);
        float tA = __shfl(A, 63), tB = __shfl(B, 63);
        cB = fmaf(tA, cB, tB);
        cA *= tA;
    }
    if (lane == 0) { tA_s[w] = cA; tB_s[w] = cB; }
    __syncthreads();
    float uw = 0.f;
    for (int s2 = 0; s2 < w; ++s2) uw = fmaf(tA_s[s2], uw, tB_s[s2]);
    #pragma unroll
    for (int g = 0; g < GPW; ++g) {
        int c = (w * GPW + g) * 64 + lane;
        if (c < NC) u0[c * M + j] = fmaf(PA[g], uw, PB[g]);
    }
}

// ---------------------------------------------------------------- K4
__global__ __launch_bounds__(256, 8)
void k4_light(const _Float16* __restrict__ pre, const float* __restrict__ u0,
              const _Float16* __restrict__ wlogpre, const float* __restrict__ bLog,
              float* __restrict__ out)
{
    __shared__ _Float16 z_s[64 * 72];
    const int tid = threadIdx.x, lane = tid & 63, w = tid >> 6;
    const int arow = lane & 15, kb = lane >> 4;
    const int t0 = blockIdx.x * CH;

    float u0v[4];
    #pragma unroll
    for (int c = 0; c < 4; ++c) u0v[c] = u0[blockIdx.x * 64 + c * 16 + arow];

    const _Float16* prebase = pre + (size_t)blockIdx.x * 8192;
    #pragma unroll
    for (int c = 0; c < 4; ++c) {
        f16x8 pv = *(const f16x8*)&prebase[((((w * 4 + kb) * 4 + c) * 16 + arow) * 4) * 2];
        #pragma unroll
        for (int reg = 0; reg < 4; ++reg) {
            int rl = w * 16 + kb * 4 + reg;
            float z = fmaf((float)pv[2 * reg], u0v[c], (float)pv[2 * reg + 1]);
            z_s[rl * 72 + c * 16 + arow] = (_Float16)z;
        }
    }
    __syncthreads();

    f32x4 acc2[4];
    #pragma unroll
    for (int ct = 0; ct < 4; ++ct) acc2[ct] = (f32x4){0.f, 0.f, 0.f, 0.f};
    #pragma unroll
    for (int ks = 0; ks < 2; ++ks) {
        f16x8 af = *(const f16x8*)&z_s[(w * 16 + arow) * 72 + ks * 32 + kb * 8];
        #pragma unroll
        for (int ct = 0; ct < 4; ++ct) {
            f16x8 bf = *(const f16x8*)&wlogpre[((ks * 4 + kb) * 64 + ct * 16 + arow) * 8];
            acc2[ct] = __builtin_amdgcn_mfma_f32_16x16x32_f16(af, bf, acc2[ct], 0, 0, 0);
        }
    }
    #pragma unroll
    for (int ct = 0; ct < 4; ++ct) {
        float bv = bLog[ct * 16 + arow];
        #pragma unroll
        for (int reg = 0; reg < 4; ++reg) {
            int t = t0 + w * 16 + kb * 4 + reg;
            if (t < NF)
                __builtin_nontemporal_store(acc2[ct][reg] + bv,
                                            &out[t * M + ct * 16 + arow]);
        }
    }
}

// ---------------------------------------------------------------- host
extern "C" void kernel_launch(void* const* d_in, const int* in_sizes, int n_in,
                              void* d_out, int out_size, void* d_ws, size_t ws_size,
                              hipStream_t stream)
{
    const float* X    = (const float*)d_in[0];
    const float* WL   = (const float*)d_in[2];
    const float* bL   = (const float*)d_in[3];
    const float* WR   = (const float*)d_in[4];
    const float* bR   = (const float*)d_in[5];
    const float* WLog = (const float*)d_in[6];
    const float* bLog = (const float*)d_in[7];

    // ws layout (~134 MB):
    _Float16* pre = (_Float16*)d_ws;                       // NC*8192 halfs (128 MB)
    float* sA = (float*)((char*)d_ws + (size_t)NC * 8192 * 2);
    float* sB = sA + (size_t)64 * NC;
    float* u0 = sB + (size_t)64 * NC;
    _Float16* wpre    = (_Float16*)(u0 + (size_t)64 * NC); // 16384 halfs
    _Float16* wlogpre = wpre + 16384;                      // 4096 halfs

    k0_pack<<<20, 256, 0, stream>>>(WL, WR, WLog, wpre, wlogpre);
    k1_prefix<<<K1GRID, 256, 0, stream>>>(X, wpre, bL, bR, sA, sB, pre);
    k3_scan<<<M, 512, 0, stream>>>(sA, sB, u0);
    k4_light<<<NC, 256, 0, stream>>>(pre, u0, wlogpre, bLog, (float*)d_out);
}

// Round 15
// 144.722 us; speedup vs baseline: 1.2284x; 1.0030x over previous
//
#include <hip/hip_runtime.h>
#include <hip/hip_fp16.h>

// DeductronCTC v14 (= v13 + 2-deep X pipeline in K1, 3 blocks/CU):
//   K0: pre-pack WL|WR and W_logit into MFMA fragment layout (f16) in ws.
//   K1: persistent 1024 blocks; W staged to LDS once; two X register buffers
//       alternate chunks so each HBM load is issued ~1 full iteration before
//       use. Emits per-row chunk-exclusive prefixes (PA,PB) + summaries.
//   K3: 2-level scan of chunk summaries -> u0 (512 thr).
//   K4: z = PA*u0 + PB, logits MFMA; cached pre loads, NT out stores.
// Replay-safe: no buffer both read+written by a kernel, no aliasing.

constexpr int NF  = 500000;
constexpr int KIN = 128;
constexpr int M   = 64;
constexpr int CH  = 64;
constexpr int NC  = (NF + CH - 1) / CH;   // 7813
constexpr int NG  = (NC + 63) / 64;       // 123
constexpr int K3W = 8;
constexpr int GPW = (NG + K3W - 1) / K3W; // 16
constexpr int K1GRID = 1024;

typedef _Float16 f16x8 __attribute__((ext_vector_type(8)));
typedef __fp16   fp16x2 __attribute__((ext_vector_type(2)));
typedef float    f32x4 __attribute__((ext_vector_type(4)));

__device__ __forceinline__ float sig(float x) {
    return __builtin_amdgcn_rcpf(1.0f + __expf(-x));
}

// ---------------------------------------------------------------- K0
__global__ void k0_pack(const float* __restrict__ WL, const float* __restrict__ WR,
                        const float* __restrict__ WLog,
                        _Float16* __restrict__ wpre, _Float16* __restrict__ wlogpre)
{
    int flat = blockIdx.x * 1024 + threadIdx.x * 4;
    if (flat < 16384) {
        int k = flat >> 7, col = flat & 127;
        float4 v = (col < 64) ? *(const float4*)&WL[k * 64 + col]
                              : *(const float4*)&WR[k * 64 + (col - 64)];
        int kb = k >> 3, kj = k & 7;
        wpre[(kb * 128 + col + 0) * 8 + kj] = (_Float16)v.x;
        wpre[(kb * 128 + col + 1) * 8 + kj] = (_Float16)v.y;
        wpre[(kb * 128 + col + 2) * 8 + kj] = (_Float16)v.z;
        wpre[(kb * 128 + col + 3) * 8 + kj] = (_Float16)v.w;
    } else if (flat < 16384 + 4096) {
        int f2 = flat - 16384;
        int k = f2 >> 6, c = f2 & 63;
        float4 v = *(const float4*)&WLog[f2];
        int kb = k >> 3, kj = k & 7;
        wlogpre[(kb * 64 + c + 0) * 8 + kj] = (_Float16)v.x;
        wlogpre[(kb * 64 + c + 1) * 8 + kj] = (_Float16)v.y;
        wlogpre[(kb * 64 + c + 2) * 8 + kj] = (_Float16)v.z;
        wlogpre[(kb * 64 + c + 3) * 8 + kj] = (_Float16)v.w;
    }
}

// load one chunk's X rows into an 8x f32x4 register buffer
#define LOADX(buf, cc)                                                        \
    {                                                                         \
        const int xrow_ = (cc) * CH + w * 16 + arow;                          \
        const float* xp_ = X + (size_t)xrow_ * KIN;                           \
        const bool ok_ = ((cc) < NC) && (xrow_ < NF);                         \
        _Pragma("unroll")                                                     \
        for (int s = 0; s < 4; ++s) {                                         \
            buf[2 * s]     = ok_ ? *(const f32x4*)&xp_[s * 32 + kb * 8]       \
                                 : (f32x4){0.f, 0.f, 0.f, 0.f};               \
            buf[2 * s + 1] = ok_ ? *(const f32x4*)&xp_[s * 32 + kb * 8 + 4]   \
                                 : (f32x4){0.f, 0.f, 0.f, 0.f};               \
        }                                                                     \
    }

// full per-chunk body: MFMA from `buf`, then refill `buf` with chunk cc+2G,
// then sigmoid/scan/emit epilogue for chunk cc.
#define PROCESS(cc, buf)                                                      \
    {                                                                         \
        const int t0 = (cc) * CH;                                             \
        f32x4 acc[8];                                                         \
        _Pragma("unroll")                                                     \
        for (int c = 0; c < 8; ++c) acc[c] = (f32x4){0.f, 0.f, 0.f, 0.f};     \
        _Pragma("unroll")                                                     \
        for (int s = 0; s < 4; ++s) {                                         \
            fp16x2 p0 = __builtin_amdgcn_cvt_pkrtz(buf[2*s].x, buf[2*s].y);   \
            fp16x2 p1 = __builtin_amdgcn_cvt_pkrtz(buf[2*s].z, buf[2*s].w);   \
            fp16x2 p2 = __builtin_amdgcn_cvt_pkrtz(buf[2*s+1].x, buf[2*s+1].y);\
            fp16x2 p3 = __builtin_amdgcn_cvt_pkrtz(buf[2*s+1].z, buf[2*s+1].w);\
            f16x8 af = { (_Float16)p0[0], (_Float16)p0[1],                    \
                         (_Float16)p1[0], (_Float16)p1[1],                    \
                         (_Float16)p2[0], (_Float16)p2[1],                    \
                         (_Float16)p3[0], (_Float16)p3[1] };                  \
            _Pragma("unroll")                                                 \
            for (int c = 0; c < 8; ++c) {                                     \
                f16x8 bf = *(const f16x8*)&w_s[((s*4+kb)*128 + c*16 + arow)*8];\
                acc[c] = __builtin_amdgcn_mfma_f32_16x16x32_f16(af, bf, acc[c], 0, 0, 0); \
            }                                                                 \
        }                                                                     \
        LOADX(buf, (cc) + 2 * K1GRID);   /* refill ~1 iter ahead of use */    \
        float a[4][4], b[4][4];                                               \
        _Pragma("unroll")                                                     \
        for (int c = 0; c < 4; ++c) {                                         \
            _Pragma("unroll")                                                 \
            for (int reg = 0; reg < 4; ++reg) {                               \
                float lv = sig(acc[c][reg] + blv[c]);                         \
                float rv = sig(acc[c + 4][reg] + brv[c]);                     \
                a[c][reg] = lv * rv;                                          \
                b[c][reg] = 1.0f - lv;                                        \
            }                                                                 \
        }                                                                     \
        float Ai[4], Bi[4];                                                   \
        _Pragma("unroll")                                                     \
        for (int c = 0; c < 4; ++c) {                                         \
            float A = 1.f, B = 0.f;                                           \
            _Pragma("unroll")                                                 \
            for (int reg = 0; reg < 4; ++reg) {                               \
                if (t0 + w * 16 + kb * 4 + reg < NF - 1) {                    \
                    B = fmaf(a[c][reg], B, b[c][reg]);                        \
                    A *= a[c][reg];                                           \
                }                                                             \
            }                                                                 \
            Ai[c] = A; Bi[c] = B;                                             \
        }                                                                     \
        _Pragma("unroll")                                                     \
        for (int d = 16; d < 64; d <<= 1) {                                   \
            _Pragma("unroll")                                                 \
            for (int c = 0; c < 4; ++c) {                                     \
                float pA = __shfl_up(Ai[c], d), pB = __shfl_up(Bi[c], d);     \
                if (lane >= d) { Bi[c] = fmaf(Ai[c], pB, Bi[c]); Ai[c] *= pA; }\
            }                                                                 \
        }                                                                     \
        float eA[4], eB[4];                                                   \
        _Pragma("unroll")                                                     \
        for (int c = 0; c < 4; ++c) {                                         \
            eA[c] = __shfl_up(Ai[c], 16);                                     \
            eB[c] = __shfl_up(Bi[c], 16);                                     \
            if (kb == 0) { eA[c] = 1.f; eB[c] = 0.f; }                        \
        }                                                                     \
        if (kb == 3) {                                                        \
            _Pragma("unroll")                                                 \
            for (int c = 0; c < 4; ++c) {                                     \
                pA_s[w * 64 + c * 16 + arow] = Ai[c];                         \
                pB_s[w * 64 + c * 16 + arow] = Bi[c];                         \
            }                                                                 \
        }                                                                     \
        __syncthreads();                                                      \
        float EA[4] = {1.f, 1.f, 1.f, 1.f}, EB[4] = {0.f, 0.f, 0.f, 0.f};     \
        for (int s2 = 0; s2 < w; ++s2) {                                      \
            _Pragma("unroll")                                                 \
            for (int c = 0; c < 4; ++c) {                                     \
                float qa = pA_s[s2 * 64 + c * 16 + arow];                     \
                float qb = pB_s[s2 * 64 + c * 16 + arow];                     \
                EB[c] = fmaf(qa, EB[c], qb);                                  \
                EA[c] *= qa;                                                  \
            }                                                                 \
        }                                                                     \
        _Float16* prebase = pre + (size_t)(cc) * 8192;                        \
        _Pragma("unroll")                                                     \
        for (int c = 0; c < 4; ++c) {                                         \
            float pa = eA[c] * EA[c];                                         \
            float pb = fmaf(eA[c], EB[c], eB[c]);                             \
            f16x8 sv;                                                         \
            _Pragma("unroll")                                                 \
            for (int reg = 0; reg < 4; ++reg) {                               \
                fp16x2 pp = __builtin_amdgcn_cvt_pkrtz(pa, pb);               \
                sv[2 * reg]     = (_Float16)pp[0];                            \
                sv[2 * reg + 1] = (_Float16)pp[1];                            \
                if (t0 + w * 16 + kb * 4 + reg < NF - 1) {                    \
                    pb = fmaf(a[c][reg], pb, b[c][reg]);                      \
                    pa *= a[c][reg];                                          \
                }                                                             \
            }                                                                 \
            *(f16x8*)&prebase[((((w * 4 + kb) * 4 + c) * 16 + arow) * 4) * 2] = sv; \
        }                                                                     \
        if (tid < 64) {                                                       \
            float At = 1.f, Bt = 0.f;                                         \
            _Pragma("unroll")                                                 \
            for (int s2 = 0; s2 < 4; ++s2) {                                  \
                float qa = pA_s[s2 * 64 + tid], qb = pB_s[s2 * 64 + tid];     \
                Bt = fmaf(qa, Bt, qb);                                        \
                At *= qa;                                                     \
            }                                                                 \
            sA[tid * NC + (cc)] = At;                                         \
            sB[tid * NC + (cc)] = Bt;                                         \
        }                                                                     \
        __syncthreads();                                                      \
    }

// ---------------------------------------------------------------- K1
__global__ __launch_bounds__(256, 3)
void k1_prefix(const float* __restrict__ X, const _Float16* __restrict__ wpre,
               const float* __restrict__ bL, const float* __restrict__ bR,
               float* __restrict__ sA, float* __restrict__ sB,
               _Float16* __restrict__ pre)
{
    __shared__ _Float16 w_s[16384];
    __shared__ float pA_s[256], pB_s[256];
    const int tid = threadIdx.x, lane = tid & 63, w = tid >> 6;
    const int arow = lane & 15, kb = lane >> 4;

    #pragma unroll
    for (int i = 0; i < 8; ++i) {
        int c16 = i * 256 + tid;
        *(f16x8*)&w_s[c16 * 8] = ((const f16x8*)wpre)[c16];
    }
    __syncthreads();

    float blv[4], brv[4];
    #pragma unroll
    for (int c = 0; c < 4; ++c) { blv[c] = bL[c * 16 + arow]; brv[c] = bR[c * 16 + arow]; }

    f32x4 xva[8], xvb[8];
    int cid = blockIdx.x;
    LOADX(xva, cid);
    LOADX(xvb, cid + K1GRID);

    while (true) {
        PROCESS(cid, xva);
        cid += K1GRID;
        if (cid >= NC) break;
        PROCESS(cid, xvb);
        cid += K1GRID;
        if (cid >= NC) break;
    }
}

// ---------------------------------------------------------------- K3
__global__ __launch_bounds__(512)
void k3_scan(const float* __restrict__ sA, const float* __restrict__ sB,
             float* __restrict__ u0)
{
    __shared__ float tA_s[K3W], tB_s[K3W];
    const int j    = blockIdx.x;
    const int lane = threadIdx.x & 63;
    const int w    = threadIdx.x >> 6;

    float PA[GPW], PB[GPW];
    float cA = 1.f, cB = 0.f;
    #pragma unroll
    for (int g = 0; g < GPW; ++g) {
        int c = (w * GPW + g) * 64 + lane;
        float A = 1.f, B = 0.f;
        if (c < NC) { A = sA[j * NC + c]; B = sB[j * NC + c]; }
        #pragma unroll
        for (int d = 1; d < 64; d <<= 1) {
            float pA = __shfl_up(A, d), pB = __shfl_up(B, d);
            if (lane >= d) { B = fmaf(A, pB, B); A *= pA; }
        }
        float eA = __shfl_up(A, 1), eB = __shfl_up(B, 1);
        if (lane == 0) { eA = 1.f; eB = 0.f; }
        PA[g] = eA * cA;
        PB[g] = fmaf(eA, cB, eB);
        float tA = __shfl(A, 63), tB = __shfl(B, 63);
        cB = fmaf(tA, cB, tB);
        cA *= tA;
    }
    if (lane == 0) { tA_s[w] = cA; tB_s[w] = cB; }
    __syncthreads();
    float uw = 0.f;
    for (int s2 = 0; s2 < w; ++s2) uw = fmaf(tA_s[s2], uw, tB_s[s2]);
    #pragma unroll
    for (int g = 0; g < GPW; ++g) {
        int c = (w * GPW + g) * 64 + lane;
        if (c < NC) u0[c * M + j] = fmaf(PA[g], uw, PB[g]);
    }
}

// ---------------------------------------------------------------- K4
__global__ __launch_bounds__(256, 8)
void k4_light(const _Float16* __restrict__ pre, const float* __restrict__ u0,
              const _Float16* __restrict__ wlogpre, const float* __restrict__ bLog,
              float* __restrict__ out)
{
    __shared__ _Float16 z_s[64 * 72];
    const int tid = threadIdx.x, lane = tid & 63, w = tid >> 6;
    const int arow = lane & 15, kb = lane >> 4;
    const int t0 = blockIdx.x * CH;

    float u0v[4];
    #pragma unroll
    for (int c = 0; c < 4; ++c) u0v[c] = u0[blockIdx.x * 64 + c * 16 + arow];

    const _Float16* prebase = pre + (size_t)blockIdx.x * 8192;
    #pragma unroll
    for (int c = 0; c < 4; ++c) {
        f16x8 pv = *(const f16x8*)&prebase[((((w * 4 + kb) * 4 + c) * 16 + arow) * 4) * 2];
        #pragma unroll
        for (int reg = 0; reg < 4; ++reg) {
            int rl = w * 16 + kb * 4 + reg;
            float z = fmaf((float)pv[2 * reg], u0v[c], (float)pv[2 * reg + 1]);
            z_s[rl * 72 + c * 16 + arow] = (_Float16)z;
        }
    }
    __syncthreads();

    f32x4 acc2[4];
    #pragma unroll
    for (int ct = 0; ct < 4; ++ct) acc2[ct] = (f32x4){0.f, 0.f, 0.f, 0.f};
    #pragma unroll
    for (int ks = 0; ks < 2; ++ks) {
        f16x8 af = *(const f16x8*)&z_s[(w * 16 + arow) * 72 + ks * 32 + kb * 8];
        #pragma unroll
        for (int ct = 0; ct < 4; ++ct) {
            f16x8 bf = *(const f16x8*)&wlogpre[((ks * 4 + kb) * 64 + ct * 16 + arow) * 8];
            acc2[ct] = __builtin_amdgcn_mfma_f32_16x16x32_f16(af, bf, acc2[ct], 0, 0, 0);
        }
    }
    #pragma unroll
    for (int ct = 0; ct < 4; ++ct) {
        float bv = bLog[ct * 16 + arow];
        #pragma unroll
        for (int reg = 0; reg < 4; ++reg) {
            int t = t0 + w * 16 + kb * 4 + reg;
            if (t < NF)
                __builtin_nontemporal_store(acc2[ct][reg] + bv,
                                            &out[t * M + ct * 16 + arow]);
        }
    }
}

// ---------------------------------------------------------------- host
extern "C" void kernel_launch(void* const* d_in, const int* in_sizes, int n_in,
                              void* d_out, int out_size, void* d_ws, size_t ws_size,
                              hipStream_t stream)
{
    const float* X    = (const float*)d_in[0];
    const float* WL   = (const float*)d_in[2];
    const float* bL   = (const float*)d_in[3];
    const float* WR   = (const float*)d_in[4];
    const float* bR   = (const float*)d_in[5];
    const float* WLog = (const float*)d_in[6];
    const float* bLog = (const float*)d_in[7];

    _Float16* pre = (_Float16*)d_ws;                       // NC*8192 halfs (128 MB)
    float* sA = (float*)((char*)d_ws + (size_t)NC * 8192 * 2);
    float* sB = sA + (size_t)64 * NC;
    float* u0 = sB + (size_t)64 * NC;
    _Float16* wpre    = (_Float16*)(u0 + (size_t)64 * NC); // 16384 halfs
    _Float16* wlogpre = wpre + 16384;                      // 4096 halfs

    k0_pack<<<20, 256, 0, stream>>>(WL, WR, WLog, wpre, wlogpre);
    k1_prefix<<<K1GRID, 256, 0, stream>>>(X, wpre, bL, bR, sA, sB, pre);
    k3_scan<<<M, 512, 0, stream>>>(sA, sB, u0);
    k4_light<<<NC, 256, 0, stream>>>(pre, u0, wlogpre, bLog, (float*)d_out);
}